// Round 15
// baseline (151.781 us; speedup 1.0000x reference)
//
#include <hip/hip_runtime.h>

#define B_SZ   8
#define SEQ    2048
#define PSEQ   (SEQ+16)     // 16 zero pad rows before each batch
#define SDIM   1024
#define DIN    512
#define DOUT   512
#define KX     10
#define RTOT   (B_SZ*SEQ)   // 16384
#define LC     64
#define NC     (SEQ/LC)     // 32

typedef __attribute__((ext_vector_type(8))) short short8;
typedef __attribute__((ext_vector_type(4))) float f32x4;
typedef __attribute__((ext_vector_type(4))) unsigned short bfx4;

// ---- workspace layout (bytes). Xp has 64 slack rows for X-prefetch overread.
#define OFF_XP   0UL             // (B_SZ*PSEQ+64)*DIN*2 = 16,973,824
#define OFF_UB   16973824UL      // RTOT*SDIM*2 (bf16)   = 33,554,432
#define OFF_HS   50528256UL      // RTOT*SDIM*2 (bf16)   = 33,554,432
#define OFF_BT   84082688UL      // SDIM*DIN*2           = 1,048,576
#define OFF_CT   85131264UL      // DOUT*SDIM*2          = 1,048,576
#define OFF_MT   86179840UL      // KX*DOUT*DIN*2        = 5,242,880

__device__ __forceinline__ short f2bf(float f) {
  unsigned u = __builtin_bit_cast(unsigned, f);
  u += 0x7fffu + ((u >> 16) & 1u);   // RNE
  return (short)(u >> 16);
}
__device__ __forceinline__ float bf2f(unsigned short b) {
  return __builtin_bit_cast(float, (unsigned)b << 16);
}

#define GLOAD16(gp, lp) __builtin_amdgcn_global_load_lds( \
    (const __attribute__((address_space(1))) void*)(gp), \
    (__attribute__((address_space(3))) void*)(lp), 16, 0, 0)
#define WAITVM(n) asm volatile("s_waitcnt vmcnt(" #n ")" ::: "memory")
#define LGKM0()   do { asm volatile("s_waitcnt lgkmcnt(0)" ::: "memory"); \
                       __builtin_amdgcn_sched_barrier(0); } while (0)
#define SBAR() __builtin_amdgcn_s_barrier()

// ================= shared GEMM pipeline building blocks (8-wave, GEMM1) ======
struct Frags { short8 a[4][2]; short8 b[4][2]; };

__device__ __forceinline__ void read_frags(Frags& f, const short* la, int aoff,
                                           const short* lb, int lane, int wm, int wn) {
  int lr = lane & 15, h = lane >> 4;
  #pragma unroll
  for (int kk = 0; kk < 2; ++kk) {
    int kslot = kk * 4 + h;
    #pragma unroll
    for (int mi = 0; mi < 4; ++mi) {
      int row = aoff + wm * 64 + mi * 16 + lr;
      f.a[mi][kk] = *reinterpret_cast<const short8*>(la + row * 64 + ((kslot ^ (row & 7)) << 3));
    }
    #pragma unroll
    for (int ni = 0; ni < 4; ++ni) {
      int row = wn * 64 + ni * 16 + lr;
      f.b[ni][kk] = *reinterpret_cast<const short8*>(lb + row * 64 + ((kslot ^ (row & 7)) << 3));
    }
  }
}

__device__ __forceinline__ void mfma_frags(const Frags& f, f32x4 acc[4][4]) {
  #pragma unroll
  for (int kk = 0; kk < 2; ++kk)
    #pragma unroll
    for (int mi = 0; mi < 4; ++mi)
      #pragma unroll
      for (int ni = 0; ni < 4; ++ni)
        acc[mi][ni] = __builtin_amdgcn_mfma_f32_16x16x32_bf16(f.a[mi][kk], f.b[ni][kk], acc[mi][ni], 0, 0, 0);
}

__device__ __forceinline__ void sgb_interleave() {
  #pragma unroll
  for (int i = 0; i < 16; ++i) {
    __builtin_amdgcn_sched_group_barrier(0x008, 2, 0);   // 2 MFMA
    __builtin_amdgcn_sched_group_barrier(0x100, 1, 0);   // 1 DS read
  }
}

// 512-thread stagers (GEMM1)
__device__ __forceinline__ void stageA256(const short* __restrict__ g, int ld,
                                          short* l, int tid) {
  int rsub = tid >> 3;
  int slot = (tid & 7) ^ (rsub & 7);
  #pragma unroll
  for (int i = 0; i < 4; ++i) {
    int row = i * 64 + rsub;
    GLOAD16(g + (size_t)row * ld + slot * 8, l + row * 64 + (tid & 7) * 8);
  }
}
__device__ __forceinline__ void stageB128(const short* __restrict__ g, int ld,
                                          short* l, int tid) {
  int rsub = tid >> 3;
  int slot = (tid & 7) ^ (rsub & 7);
  #pragma unroll
  for (int i = 0; i < 2; ++i) {
    int row = i * 64 + rsub;
    GLOAD16(g + (size_t)row * ld + slot * 8, l + row * 64 + (tid & 7) * 8);
  }
}

// 256-thread stagers (GEMM2, 4-wave)
__device__ __forceinline__ void stageA256_4(const short* __restrict__ g, int ld,
                                            short* l, int tid) {
  int rsub = tid >> 3;                 // 0..31
  int slot = (tid & 7) ^ (rsub & 7);
  #pragma unroll
  for (int i = 0; i < 8; ++i) {
    int row = i * 32 + rsub;
    GLOAD16(g + (size_t)row * ld + slot * 8, l + row * 64 + (tid & 7) * 8);
  }
}
__device__ __forceinline__ void stageB128_4(const short* __restrict__ g, int ld,
                                            short* l, int tid) {
  int rsub = tid >> 3;
  int slot = (tid & 7) ^ (rsub & 7);
  #pragma unroll
  for (int i = 0; i < 4; ++i) {
    int row = i * 32 + rsub;
    GLOAD16(g + (size_t)row * ld + slot * 8, l + row * 64 + (tid & 7) * 8);
  }
}
__device__ __forceinline__ void stageX272_4(const short* __restrict__ g,
                                            short* l, int tid) {
  stageA256_4(g, DIN, l, tid);
  if (tid < 128) {
    int rsub = tid >> 3;
    int row = 256 + rsub;
    int slot = (tid & 7) ^ (row & 7);
    GLOAD16(g + (size_t)row * DIN + slot * 8, l + row * 64 + (tid & 7) * 8);
  }
}

// ================= prep1: conv+pad x | transpose B =================
__global__ void k_prep1(const float* __restrict__ x, const float* __restrict__ B,
                        short* __restrict__ Xp, short* __restrict__ Bt) {
  __shared__ float t[32][33];
  int blk = blockIdx.x, tid = threadIdx.x;
  if (blk < 2048) {
    const int NG = RTOT * (DIN / 8);
    const int NPAD = B_SZ * 16 * (DIN / 8);
    for (int g = blk * 256 + tid; g < NG + NPAD; g += 2048 * 256) {
      if (g < NG) {
        int r = g >> 6, c8 = g & 63;
        int b = r >> 11, tt = r & 2047;
        const float4* p = reinterpret_cast<const float4*>(x) + (size_t)g * 2;
        float4 f0 = p[0], f1 = p[1];
        short8 o;
        o[0]=f2bf(f0.x); o[1]=f2bf(f0.y); o[2]=f2bf(f0.z); o[3]=f2bf(f0.w);
        o[4]=f2bf(f1.x); o[5]=f2bf(f1.y); o[6]=f2bf(f1.z); o[7]=f2bf(f1.w);
        *reinterpret_cast<short8*>(Xp + ((size_t)(b * PSEQ + 16 + tt) * DIN + c8 * 8)) = o;
      } else {
        int idx = g - NG;
        int b = idx >> 10, rem = idx & 1023;
        int row16 = rem >> 6, c8 = rem & 63;
        const short8 z = {0,0,0,0,0,0,0,0};
        *reinterpret_cast<short8*>(Xp + ((size_t)(b * PSEQ + row16) * DIN + c8 * 8)) = z;
      }
    }
  } else {
    int idx = blk - 2048;                 // B: [DIN x SDIM] -> Bt [SDIM][DIN]
    int bx = (idx & 31) * 32, by = (idx >> 5) * 32;
    int tx = tid & 31, ty = tid >> 5;
    #pragma unroll
    for (int j = 0; j < 32; j += 8)
      t[ty + j][tx] = B[(size_t)(by + ty + j) * SDIM + (bx + tx)];
    __syncthreads();
    #pragma unroll
    for (int j = 0; j < 32; j += 8)
      Bt[(size_t)(bx + ty + j) * DIN + (by + tx)] = f2bf(t[tx][ty + j]);
  }
}

// ================= scan_h (+S folded) | transpose C | prep M =================
__global__ void k_scan_h(const short* __restrict__ uB, const float* __restrict__ A,
                         const float* __restrict__ h0, const float* __restrict__ E,
                         short* __restrict__ hs,
                         const float* __restrict__ C, const float* __restrict__ M,
                         short* __restrict__ Ct, short* __restrict__ Mt) {
  __shared__ float t[32][33];
  int blk = blockIdx.x, tid = threadIdx.x;
  if (blk < 256) {
    int b = blk >> 5, c = blk & 31;
    int s0 = tid * 4;
    float a[4], h[4], ap[4];
    #pragma unroll
    for (int j = 0; j < 4; ++j) {
      a[j] = A[s0 + j];
      float p = a[j];
      #pragma unroll
      for (int q = 0; q < 6; ++q) p *= p;   // a^64
      ap[j] = p;
      h[j] = h0[s0 + j];
    }
    const float* Eb = E + (size_t)b * NC * SDIM + s0;
    for (int c2 = 0; c2 < c; ++c2) {
      float4 ev = *reinterpret_cast<const float4*>(Eb + (size_t)c2 * SDIM);
      h[0] = fmaf(ap[0], h[0], ev.x);
      h[1] = fmaf(ap[1], h[1], ev.y);
      h[2] = fmaf(ap[2], h[2], ev.z);
      h[3] = fmaf(ap[3], h[3], ev.w);
    }
    const short* base = uB + ((size_t)b * SEQ + (size_t)c * LC) * SDIM + s0;
    short* hbase = hs + ((size_t)b * SEQ + (size_t)c * LC) * SDIM + s0;
    for (int tt = 0; tt < LC; ++tt) {
      bfx4 v = *reinterpret_cast<const bfx4*>(base + (size_t)tt * SDIM);
      bfx4 o;
      #pragma unroll
      for (int j = 0; j < 4; ++j) {
        h[j] = fmaf(a[j], h[j], bf2f(v[j]));
        o[j] = (unsigned short)f2bf(h[j]);
      }
      *reinterpret_cast<bfx4*>(hbase + (size_t)tt * SDIM) = o;
    }
  } else if (blk < 768) {
    int idx = blk - 256;                  // C: [SDIM x DOUT] -> Ct [DOUT][SDIM]
    int bx = (idx & 15) * 32, by = (idx >> 4) * 32;
    int tx = tid & 31, ty = tid >> 5;
    #pragma unroll
    for (int j = 0; j < 32; j += 8)
      t[ty + j][tx] = C[(size_t)(by + ty + j) * DOUT + (bx + tx)];
    __syncthreads();
    #pragma unroll
    for (int j = 0; j < 32; j += 8)
      Ct[(size_t)(bx + ty + j) * SDIM + (by + tx)] = f2bf(t[tx][ty + j]);
  } else {
    int idx = (blk - 768) * 256 + tid;    // Mt[t][o][i] = bf16(M[o][i][t])
    if (idx < DOUT * DIN) {
      int o = idx / DIN, i = idx - o * DIN;
      const float* src = M + ((size_t)o * DIN + i) * KX;
      #pragma unroll
      for (int tt = 0; tt < KX; ++tt)
        Mt[((size_t)tt * DOUT + o) * DIN + i] = f2bf(src[tt]);
    }
  }
}

// ================= GEMM1: 256x128, 8 waves, 3-buf ring (R14, proven) ========
__global__ __launch_bounds__(512, 2) void k_gemm_uB(const short* __restrict__ Xp,
                                                    const short* __restrict__ Bt,
                                                    short* __restrict__ uB,
                                                    const float* __restrict__ Adecay,
                                                    float* __restrict__ E) {
  __shared__ __attribute__((aligned(16))) short lds[73728];   // 3 x (16384A + 8192B)
  short* const P0 = lds;
  short* const P1 = lds + 24576;
  short* const P2 = lds + 49152;
  int tid = threadIdx.x, lane = tid & 63, w = tid >> 6;
  int wm = w >> 1, wn = w & 1;                 // 4M x 2N waves, 64x64 each
  int bid = blockIdx.x;
  long r0 = (long)(bid & 63) * 256;
  int  c0 = (bid >> 6) * 128;
  int  b  = (int)(r0 >> 11);
  const short* Aa = Xp + (size_t)(r0 + 16 * (b + 1)) * DIN;
  const short* Bb = Bt + (size_t)c0 * DIN;

  const f32x4 z4 = {0.f, 0.f, 0.f, 0.f};
  f32x4 acc[4][4];
  #pragma unroll
  for (int mi = 0; mi < 4; ++mi)
    #pragma unroll
    for (int ni = 0; ni < 4; ++ni) acc[mi][ni] = z4;

  Frags fr[2];

  stageA256(Aa,       DIN, P0, tid);  stageB128(Bb,       DIN, P0 + 16384, tid);
  stageA256(Aa + 64,  DIN, P1, tid);  stageB128(Bb + 64,  DIN, P1 + 16384, tid);
  stageA256(Aa + 128, DIN, P2, tid);  stageB128(Bb + 128, DIN, P2 + 16384, tid);
  WAITVM(6);
  SBAR();
  read_frags(fr[0], P0, 0, P0 + 16384, lane, wm, wn);

  #pragma unroll
  for (int s = 0; s < 8; ++s) {
    __builtin_amdgcn_s_setprio(1);
    mfma_frags(fr[s & 1], acc);
    if (s < 7) {
      const short* nb = ((s + 1) % 3 == 0) ? P0 : ((s + 1) % 3 == 1) ? P1 : P2;
      read_frags(fr[(s + 1) & 1], nb, 0, nb + 16384, lane, wm, wn);
      sgb_interleave();
    }
    __builtin_amdgcn_s_setprio(0);
    if (s < 7) {
      LGKM0();
      SBAR();
      if (s <= 4) {
        short* sp = (s % 3 == 0) ? P0 : (s % 3 == 1) ? P1 : P2;
        stageA256(Aa + (s + 3) * 64, DIN, sp, tid);
        stageB128(Bb + (s + 3) * 64, DIN, sp + 16384, tid);
        WAITVM(6);
      } else {
        WAITVM(0);
      }
      SBAR();
    }
  }

  int h = lane >> 4;
  #pragma unroll
  for (int mi = 0; mi < 4; ++mi)
    #pragma unroll
    for (int ni = 0; ni < 4; ++ni)
      #pragma unroll
      for (int r = 0; r < 4; ++r) {
        long row = r0 + wm * 64 + mi * 16 + h * 4 + r;
        int  col = c0 + wn * 64 + ni * 16 + (lane & 15);
        uB[(size_t)row * SDIM + col] = f2bf(acc[mi][ni][r]);
      }
  int cch = (int)((r0 >> 6) & 31) + wm;
  #pragma unroll
  for (int ni = 0; ni < 4; ++ni) {
    int col = c0 + wn * 64 + ni * 16 + (lane & 15);
    float a  = Adecay[col];
    float a2 = a * a, a3 = a2 * a;
    float A4 = a2 * a2;
    float A16 = A4 * A4; A16 = A16 * A16;
    float P16_2 = A16 * A16, P16_3 = P16_2 * A16;
    float Q4 = (h == 3) ? 1.f : (h == 2) ? A4 : (h == 1) ? A4 * A4 : A4 * A4 * A4;
    float cm0 = fmaf(acc[0][ni][0], a3, fmaf(acc[0][ni][1], a2, fmaf(acc[0][ni][2], a, acc[0][ni][3])));
    float cm1 = fmaf(acc[1][ni][0], a3, fmaf(acc[1][ni][1], a2, fmaf(acc[1][ni][2], a, acc[1][ni][3])));
    float cm2 = fmaf(acc[2][ni][0], a3, fmaf(acc[2][ni][1], a2, fmaf(acc[2][ni][2], a, acc[2][ni][3])));
    float cm3 = fmaf(acc[3][ni][0], a3, fmaf(acc[3][ni][1], a2, fmaf(acc[3][ni][2], a, acc[3][ni][3])));
    float L = fmaf(cm0, P16_3, fmaf(cm1, P16_2, fmaf(cm2, A16, cm3)));
    L *= Q4;
    L += __shfl_xor(L, 16);
    L += __shfl_xor(L, 32);
    if (h == 0) E[((size_t)b * NC + cch) * SDIM + col] = L;
  }
}

// ================= GEMM2: 256x128 tile, 4 waves of 128x64, 3-buf ring ========
// LDS (shorts, 73728 = 144 KiB): P0/P1/P2 @ 0/24576/49152 (A 16384 + B 8192)
// phase2: Xs0@0 Xs1@17408 (272x64 each); PM0@36864 PM1@45056 PM2@53248 (128x64)
struct Frags4 { short8 a[8][2]; short8 b[4][2]; };

__device__ __forceinline__ void read_frags4(Frags4& f, const short* la, int aoff,
                                            const short* lb, int lane, int wm, int wn) {
  int lr = lane & 15, h = lane >> 4;
  #pragma unroll
  for (int kk = 0; kk < 2; ++kk) {
    int kslot = kk * 4 + h;
    #pragma unroll
    for (int mi = 0; mi < 8; ++mi) {
      int row = aoff + wm * 128 + mi * 16 + lr;
      f.a[mi][kk] = *reinterpret_cast<const short8*>(la + row * 64 + ((kslot ^ (row & 7)) << 3));
    }
    #pragma unroll
    for (int ni = 0; ni < 4; ++ni) {
      int row = wn * 64 + ni * 16 + lr;
      f.b[ni][kk] = *reinterpret_cast<const short8*>(lb + row * 64 + ((kslot ^ (row & 7)) << 3));
    }
  }
}

__device__ __forceinline__ void mfma_frags4(const Frags4& f, f32x4 acc[8][4]) {
  #pragma unroll
  for (int kk = 0; kk < 2; ++kk)
    #pragma unroll
    for (int mi = 0; mi < 8; ++mi)
      #pragma unroll
      for (int ni = 0; ni < 4; ++ni)
        acc[mi][ni] = __builtin_amdgcn_mfma_f32_16x16x32_bf16(f.a[mi][kk], f.b[ni][kk], acc[mi][ni], 0, 0, 0);
}

__device__ __forceinline__ void sgb_interleave4() {
  #pragma unroll
  for (int i = 0; i < 8; ++i) {
    __builtin_amdgcn_sched_group_barrier(0x008, 8, 0);   // 8 MFMA
    __builtin_amdgcn_sched_group_barrier(0x100, 3, 0);   // 3 DS read
  }
}

__global__ __launch_bounds__(256, 1) void k_gemm_out(const short* __restrict__ hs,
                                                     const short* __restrict__ Xp,
                                                     const short* __restrict__ Ct,
                                                     const short* __restrict__ Mt,
                                                     float* __restrict__ out) {
  __shared__ __attribute__((aligned(16))) short lds[73728];
  short* const P0  = lds;
  short* const P1  = lds + 24576;
  short* const P2  = lds + 49152;
  short* const Xs0 = lds;
  short* const Xs1 = lds + 17408;
  short* const PM0 = lds + 36864;
  short* const PM1 = lds + 45056;
  short* const PM2 = lds + 53248;
  int tid = threadIdx.x, lane = tid & 63, w = tid >> 6;
  int wm = w >> 1, wn = w & 1;                  // 2M x 2N waves, 128x64 each
  int bid = blockIdx.x;
  int sw  = (bid & 7) * 32 + (bid >> 3);        // XCD-bijective over 256
  long r0 = (long)(sw & 63) * 256;
  int  c0 = (sw >> 6) * 128;
  int  b  = (int)(r0 >> 11);
  const short* hsA = hs + (size_t)r0 * SDIM;
  const short* CtB = Ct + (size_t)c0 * SDIM;
  const short* Xa  = Xp + (size_t)(r0 + 16 * (b + 1) - 16) * DIN;
  const short* MtB = Mt + (size_t)c0 * DIN;

  const f32x4 z4 = {0.f, 0.f, 0.f, 0.f};
  f32x4 acc[8][4];
  #pragma unroll
  for (int mi = 0; mi < 8; ++mi)
    #pragma unroll
    for (int ni = 0; ni < 4; ++ni) acc[mi][ni] = z4;

  Frags4 fr[2];

  // ---- prologue: stage tiles 0,1,2 (12 loads each) ----
  stageA256_4(hsA,       SDIM, P0, tid);  stageB128_4(CtB,       SDIM, P0 + 16384, tid);
  stageA256_4(hsA + 64,  SDIM, P1, tid);  stageB128_4(CtB + 64,  SDIM, P1 + 16384, tid);
  stageA256_4(hsA + 128, SDIM, P2, tid);  stageB128_4(CtB + 128, SDIM, P2 + 16384, tid);
  WAITVM(12);               // tiles 0,1 landed; tile 2 in flight
  SBAR();
  read_frags4(fr[0], P0, 0, P0 + 16384, lane, wm, wn);

  // ---- phase 1: hs @ Ct^T, 16 steps ----
  #pragma unroll
  for (int s = 0; s < 16; ++s) {
    __builtin_amdgcn_s_setprio(1);
    mfma_frags4(fr[s & 1], acc);
    if (s < 15) {
      const short* nb = ((s + 1) % 3 == 0) ? P0 : ((s + 1) % 3 == 1) ? P1 : P2;
      read_frags4(fr[(s + 1) & 1], nb, 0, nb + 16384, lane, wm, wn);
    } else {
      read_frags4(fr[0], Xs0, 16, PM0, lane, wm, wn);   // phase-2 j=0 frags
    }
    sgb_interleave4();
    __builtin_amdgcn_s_setprio(0);
    LGKM0();
    SBAR();
    if (s <= 12) {
      short* sp = (s % 3 == 0) ? P0 : (s % 3 == 1) ? P1 : P2;
      stageA256_4(hsA + (s + 3) * 64, SDIM, sp, tid);
      stageB128_4(CtB + (s + 3) * 64, SDIM, sp + 16384, tid);
      WAITVM(12);             // tile s+2 landed; s+3 in flight
    } else if (s == 13) {
      stageB128_4(MtB, DIN, PM0, tid);
      stageB128_4(MtB + (size_t)DOUT * DIN, DIN, PM1, tid);
      WAITVM(8);              // tile 15 landed; M0,M1 in flight
    } else if (s == 14) {
      stageB128_4(MtB + (size_t)2 * DOUT * DIN, DIN, PM2, tid);
      stageX272_4(Xa, Xs0, tid);
      WAITVM(0);              // phase boundary: drain M0..M2 + Xs0
    }                          // s == 15: no stage
    SBAR();
  }

  // ---- phase 2: AR conv, 8 slices x 10 taps ----
  for (int k0 = 0; k0 < 8; ++k0) {
    int kc = k0 * 64;
    const short* xs = (k0 & 1) ? Xs1 : Xs0;
    short*       xn = (k0 & 1) ? Xs0 : Xs1;
    const short* q0 = (k0 % 3 == 0) ? PM0 : (k0 % 3 == 1) ? PM1 : PM2;
    const short* q1 = (k0 % 3 == 0) ? PM1 : (k0 % 3 == 1) ? PM2 : PM0;
    const short* q2 = (k0 % 3 == 0) ? PM2 : (k0 % 3 == 1) ? PM0 : PM1;
    #pragma unroll
    for (int j = 0; j < KX; ++j) {
      __builtin_amdgcn_s_setprio(1);
      mfma_frags4(fr[j & 1], acc);
      bool do_read = (j < 9) || (k0 < 7);
      if (j < 9) {
        const short* mn = ((j + 1) % 3 == 0) ? q0 : ((j + 1) % 3 == 1) ? q1 : q2;
        read_frags4(fr[(j + 1) & 1], xs, 15 - j, mn, lane, wm, wn);
      } else if (k0 < 7) {
        read_frags4(fr[0], xn, 16, q1, lane, wm, wn);   // next slice tap 0
      }
      if (do_read) sgb_interleave4();
      __builtin_amdgcn_s_setprio(0);
      LGKM0();
      SBAR();
      // stage M(j+3) (or next-slice wrap)
      if (j + 3 <= 9) {
        short* mw = (j % 3 == 0) ? (short*)q0 : (j % 3 == 1) ? (short*)q1 : (short*)q2;
        stageB128_4(MtB + (size_t)(j + 3) * DOUT * DIN + kc, DIN, mw, tid);
      } else if (k0 < 7) {
        short* mw = (j % 3 == 0) ? (short*)q0 : (j % 3 == 1) ? (short*)q1 : (short*)q2;
        stageB128_4(MtB + (size_t)(j - 7) * DOUT * DIN + kc + 64, DIN, mw, tid);
      }
      if (j == 1 && k0 < 7) stageX272_4(Xa + kc + 64, xn, tid);
      if ((j == 1 || j == 2) && k0 < 7) {
        WAITVM(12);           // leaves [M(j+2), X]; drains M(j+1)
      } else if (j >= 7 && k0 == 7) {
        WAITVM(0);            // tail
      } else {
        WAITVM(4);            // leaves newest M stage
      }
      SBAR();
    }
  }

  #pragma unroll
  for (int mi = 0; mi < 8; ++mi)
    #pragma unroll
    for (int ni = 0; ni < 4; ++ni)
      #pragma unroll
      for (int r = 0; r < 4; ++r) {
        long row = r0 + wm * 128 + mi * 16 + (lane >> 4) * 4 + r;
        int  col = c0 + wn * 64 + ni * 16 + (lane & 15);
        out[(size_t)row * DOUT + col] = acc[mi][ni][r];
      }
}

// ================= launch =================
extern "C" void kernel_launch(void* const* d_in, const int* in_sizes, int n_in,
                              void* d_out, int out_size, void* d_ws, size_t ws_size,
                              hipStream_t stream) {
  (void)in_sizes; (void)n_in; (void)out_size; (void)ws_size;
  const float* x  = (const float*)d_in[0];
  const float* h0 = (const float*)d_in[1];
  const float* A  = (const float*)d_in[2];
  const float* B  = (const float*)d_in[3];
  const float* C  = (const float*)d_in[4];
  const float* M  = (const float*)d_in[5];
  float* out = (float*)d_out;
  char* ws = (char*)d_ws;

  short* Xp  = (short*)(ws + OFF_XP);
  short* uB  = (short*)(ws + OFF_UB);
  short* hsb = (short*)(ws + OFF_HS);
  short* Bt  = (short*)(ws + OFF_BT);
  short* Ct  = (short*)(ws + OFF_CT);
  short* Mt  = (short*)(ws + OFF_MT);
  // scan scratch inside d_out (fully overwritten by k_gemm_out afterwards)
  float* E   = out;                    // B_SZ*NC*SDIM f32 = 1 MiB

  k_prep1<<<2560, 256, 0, stream>>>(x, B, Xp, Bt);
  k_gemm_uB<<<512, 512, 0, stream>>>(Xp, Bt, uB, A, E);
  k_scan_h<<<1792, 256, 0, stream>>>(uB, A, h0, E, hsb, C, M, Ct, Mt);
  k_gemm_out<<<256, 256, 0, stream>>>(hsb, Xp, Ct, Mt, out);
}

// Round 16
// 147.242 us; speedup vs baseline: 1.0308x; 1.0308x over previous
//
#include <hip/hip_runtime.h>

#define B_SZ   8
#define SEQ    2048
#define PSEQ   (SEQ+16)     // 16 zero pad rows before each batch
#define SDIM   1024
#define DIN    512
#define DOUT   512
#define KX     10
#define RTOT   (B_SZ*SEQ)   // 16384
#define LC     64
#define NC     (SEQ/LC)     // 32

typedef __attribute__((ext_vector_type(8))) short short8;
typedef __attribute__((ext_vector_type(4))) float f32x4;
typedef __attribute__((ext_vector_type(4))) unsigned short bfx4;

// ---- workspace layout (bytes). Xp has 64 slack rows for X-prefetch overread.
#define OFF_XP   0UL             // (B_SZ*PSEQ+64)*DIN*2 = 16,973,824
#define OFF_UB   16973824UL      // RTOT*SDIM*2 (bf16)   = 33,554,432
#define OFF_HS   50528256UL      // RTOT*SDIM*2 (bf16)   = 33,554,432
#define OFF_BT   84082688UL      // SDIM*DIN*2           = 1,048,576
#define OFF_CT   85131264UL      // DOUT*SDIM*2          = 1,048,576
#define OFF_MT   86179840UL      // KX*DOUT*DIN*2        = 5,242,880

__device__ __forceinline__ short f2bf(float f) {
  unsigned u = __builtin_bit_cast(unsigned, f);
  u += 0x7fffu + ((u >> 16) & 1u);   // RNE
  return (short)(u >> 16);
}
__device__ __forceinline__ float bf2f(unsigned short b) {
  return __builtin_bit_cast(float, (unsigned)b << 16);
}

#define GLOAD16(gp, lp) __builtin_amdgcn_global_load_lds( \
    (const __attribute__((address_space(1))) void*)(gp), \
    (__attribute__((address_space(3))) void*)(lp), 16, 0, 0)
#define WAITVM(n) asm volatile("s_waitcnt vmcnt(" #n ")" ::: "memory")
#define LGKM0()   do { asm volatile("s_waitcnt lgkmcnt(0)" ::: "memory"); \
                       __builtin_amdgcn_sched_barrier(0); } while (0)
#define SBAR() __builtin_amdgcn_s_barrier()

// ================= shared GEMM pipeline building blocks =================
struct Frags { short8 a[4][2]; short8 b[4][2]; };

__device__ __forceinline__ void read_frags(Frags& f, const short* la, int aoff,
                                           const short* lb, int lane, int wm, int wn) {
  int lr = lane & 15, h = lane >> 4;
  #pragma unroll
  for (int kk = 0; kk < 2; ++kk) {
    int kslot = kk * 4 + h;
    #pragma unroll
    for (int mi = 0; mi < 4; ++mi) {
      int row = aoff + wm * 64 + mi * 16 + lr;
      f.a[mi][kk] = *reinterpret_cast<const short8*>(la + row * 64 + ((kslot ^ (row & 7)) << 3));
    }
    #pragma unroll
    for (int ni = 0; ni < 4; ++ni) {
      int row = wn * 64 + ni * 16 + lr;
      f.b[ni][kk] = *reinterpret_cast<const short8*>(lb + row * 64 + ((kslot ^ (row & 7)) << 3));
    }
  }
}

__device__ __forceinline__ void mfma_frags(const Frags& f, f32x4 acc[4][4]) {
  #pragma unroll
  for (int kk = 0; kk < 2; ++kk)
    #pragma unroll
    for (int mi = 0; mi < 4; ++mi)
      #pragma unroll
      for (int ni = 0; ni < 4; ++ni)
        acc[mi][ni] = __builtin_amdgcn_mfma_f32_16x16x32_bf16(f.a[mi][kk], f.b[ni][kk], acc[mi][ni], 0, 0, 0);
}

__device__ __forceinline__ void sgb_interleave() {
  #pragma unroll
  for (int i = 0; i < 16; ++i) {
    __builtin_amdgcn_sched_group_barrier(0x008, 2, 0);   // 2 MFMA
    __builtin_amdgcn_sched_group_barrier(0x100, 1, 0);   // 1 DS read
  }
}

__device__ __forceinline__ void stageA256(const short* __restrict__ g, int ld,
                                          short* l, int tid) {
  int rsub = tid >> 3;
  int slot = (tid & 7) ^ (rsub & 7);
  #pragma unroll
  for (int i = 0; i < 4; ++i) {
    int row = i * 64 + rsub;
    GLOAD16(g + (size_t)row * ld + slot * 8, l + row * 64 + (tid & 7) * 8);
  }
}
__device__ __forceinline__ void stageB128(const short* __restrict__ g, int ld,
                                          short* l, int tid) {
  int rsub = tid >> 3;
  int slot = (tid & 7) ^ (rsub & 7);
  #pragma unroll
  for (int i = 0; i < 2; ++i) {
    int row = i * 64 + rsub;
    GLOAD16(g + (size_t)row * ld + slot * 8, l + row * 64 + (tid & 7) * 8);
  }
}
__device__ __forceinline__ void stageX320(const short* __restrict__ g,
                                          short* l, int tid) {
  int rsub = tid >> 3;
  int slot = (tid & 7) ^ (rsub & 7);
  #pragma unroll
  for (int i = 0; i < 5; ++i) {
    int row = i * 64 + rsub;
    GLOAD16(g + (size_t)row * DIN + slot * 8, l + row * 64 + (tid & 7) * 8);
  }
}

// ================= prep1: conv+pad x | transpose B =================
__global__ void k_prep1(const float* __restrict__ x, const float* __restrict__ B,
                        short* __restrict__ Xp, short* __restrict__ Bt) {
  __shared__ float t[32][33];
  int blk = blockIdx.x, tid = threadIdx.x;
  if (blk < 2048) {
    const int NG = RTOT * (DIN / 8);
    const int NPAD = B_SZ * 16 * (DIN / 8);
    for (int g = blk * 256 + tid; g < NG + NPAD; g += 2048 * 256) {
      if (g < NG) {
        int r = g >> 6, c8 = g & 63;
        int b = r >> 11, tt = r & 2047;
        const float4* p = reinterpret_cast<const float4*>(x) + (size_t)g * 2;
        float4 f0 = p[0], f1 = p[1];
        short8 o;
        o[0]=f2bf(f0.x); o[1]=f2bf(f0.y); o[2]=f2bf(f0.z); o[3]=f2bf(f0.w);
        o[4]=f2bf(f1.x); o[5]=f2bf(f1.y); o[6]=f2bf(f1.z); o[7]=f2bf(f1.w);
        *reinterpret_cast<short8*>(Xp + ((size_t)(b * PSEQ + 16 + tt) * DIN + c8 * 8)) = o;
      } else {
        int idx = g - NG;
        int b = idx >> 10, rem = idx & 1023;
        int row16 = rem >> 6, c8 = rem & 63;
        const short8 z = {0,0,0,0,0,0,0,0};
        *reinterpret_cast<short8*>(Xp + ((size_t)(b * PSEQ + row16) * DIN + c8 * 8)) = z;
      }
    }
  } else {
    int idx = blk - 2048;                 // B: [DIN x SDIM] -> Bt [SDIM][DIN]
    int bx = (idx & 31) * 32, by = (idx >> 5) * 32;
    int tx = tid & 31, ty = tid >> 5;
    #pragma unroll
    for (int j = 0; j < 32; j += 8)
      t[ty + j][tx] = B[(size_t)(by + ty + j) * SDIM + (bx + tx)];
    __syncthreads();
    #pragma unroll
    for (int j = 0; j < 32; j += 8)
      Bt[(size_t)(bx + ty + j) * DIN + (by + tx)] = f2bf(t[tx][ty + j]);
  }
}

// ================= scan_h (+S folded) | transpose C | prep M =================
__global__ void k_scan_h(const short* __restrict__ uB, const float* __restrict__ A,
                         const float* __restrict__ h0, const float* __restrict__ E,
                         short* __restrict__ hs,
                         const float* __restrict__ C, const float* __restrict__ M,
                         short* __restrict__ Ct, short* __restrict__ Mt) {
  __shared__ float t[32][33];
  int blk = blockIdx.x, tid = threadIdx.x;
  if (blk < 256) {
    int b = blk >> 5, c = blk & 31;
    int s0 = tid * 4;
    float a[4], h[4], ap[4];
    #pragma unroll
    for (int j = 0; j < 4; ++j) {
      a[j] = A[s0 + j];
      float p = a[j];
      #pragma unroll
      for (int q = 0; q < 6; ++q) p *= p;   // a^64
      ap[j] = p;
      h[j] = h0[s0 + j];
    }
    const float* Eb = E + (size_t)b * NC * SDIM + s0;
    for (int c2 = 0; c2 < c; ++c2) {
      float4 ev = *reinterpret_cast<const float4*>(Eb + (size_t)c2 * SDIM);
      h[0] = fmaf(ap[0], h[0], ev.x);
      h[1] = fmaf(ap[1], h[1], ev.y);
      h[2] = fmaf(ap[2], h[2], ev.z);
      h[3] = fmaf(ap[3], h[3], ev.w);
    }
    const short* base = uB + ((size_t)b * SEQ + (size_t)c * LC) * SDIM + s0;
    short* hbase = hs + ((size_t)b * SEQ + (size_t)c * LC) * SDIM + s0;
    for (int tt = 0; tt < LC; ++tt) {
      bfx4 v = *reinterpret_cast<const bfx4*>(base + (size_t)tt * SDIM);
      bfx4 o;
      #pragma unroll
      for (int j = 0; j < 4; ++j) {
        h[j] = fmaf(a[j], h[j], bf2f(v[j]));
        o[j] = (unsigned short)f2bf(h[j]);
      }
      *reinterpret_cast<bfx4*>(hbase + (size_t)tt * SDIM) = o;
    }
  } else if (blk < 768) {
    int idx = blk - 256;                  // C: [SDIM x DOUT] -> Ct [DOUT][SDIM]
    int bx = (idx & 15) * 32, by = (idx >> 4) * 32;
    int tx = tid & 31, ty = tid >> 5;
    #pragma unroll
    for (int j = 0; j < 32; j += 8)
      t[ty + j][tx] = C[(size_t)(by + ty + j) * DOUT + (bx + tx)];
    __syncthreads();
    #pragma unroll
    for (int j = 0; j < 32; j += 8)
      Ct[(size_t)(bx + ty + j) * SDIM + (by + tx)] = f2bf(t[tx][ty + j]);
  } else {
    int idx = (blk - 768) * 256 + tid;    // Mt[t][o][i] = bf16(M[o][i][t])
    if (idx < DOUT * DIN) {
      int o = idx / DIN, i = idx - o * DIN;
      const float* src = M + ((size_t)o * DIN + i) * KX;
      #pragma unroll
      for (int tt = 0; tt < KX; ++tt)
        Mt[((size_t)tt * DOUT + o) * DIN + i] = f2bf(src[tt]);
    }
  }
}

// ================= GEMM1: 256x128, 8 waves, 3-buf ring (R14, proven) ========
__global__ __launch_bounds__(512, 2) void k_gemm_uB(const short* __restrict__ Xp,
                                                    const short* __restrict__ Bt,
                                                    short* __restrict__ uB,
                                                    const float* __restrict__ Adecay,
                                                    float* __restrict__ E) {
  __shared__ __attribute__((aligned(16))) short lds[73728];   // 3 x (16384A + 8192B)
  short* const P0 = lds;
  short* const P1 = lds + 24576;
  short* const P2 = lds + 49152;
  int tid = threadIdx.x, lane = tid & 63, w = tid >> 6;
  int wm = w >> 1, wn = w & 1;                 // 4M x 2N waves, 64x64 each
  int bid = blockIdx.x;
  long r0 = (long)(bid & 63) * 256;
  int  c0 = (bid >> 6) * 128;
  int  b  = (int)(r0 >> 11);
  const short* Aa = Xp + (size_t)(r0 + 16 * (b + 1)) * DIN;
  const short* Bb = Bt + (size_t)c0 * DIN;

  const f32x4 z4 = {0.f, 0.f, 0.f, 0.f};
  f32x4 acc[4][4];
  #pragma unroll
  for (int mi = 0; mi < 4; ++mi)
    #pragma unroll
    for (int ni = 0; ni < 4; ++ni) acc[mi][ni] = z4;

  Frags fr[2];

  stageA256(Aa,       DIN, P0, tid);  stageB128(Bb,       DIN, P0 + 16384, tid);
  stageA256(Aa + 64,  DIN, P1, tid);  stageB128(Bb + 64,  DIN, P1 + 16384, tid);
  stageA256(Aa + 128, DIN, P2, tid);  stageB128(Bb + 128, DIN, P2 + 16384, tid);
  WAITVM(6);
  SBAR();
  read_frags(fr[0], P0, 0, P0 + 16384, lane, wm, wn);

  #pragma unroll
  for (int s = 0; s < 8; ++s) {
    __builtin_amdgcn_s_setprio(1);
    mfma_frags(fr[s & 1], acc);
    if (s < 7) {
      const short* nb = ((s + 1) % 3 == 0) ? P0 : ((s + 1) % 3 == 1) ? P1 : P2;
      read_frags(fr[(s + 1) & 1], nb, 0, nb + 16384, lane, wm, wn);
      sgb_interleave();
    }
    __builtin_amdgcn_s_setprio(0);
    if (s < 7) {
      LGKM0();
      SBAR();
      if (s <= 4) {
        short* sp = (s % 3 == 0) ? P0 : (s % 3 == 1) ? P1 : P2;
        stageA256(Aa + (s + 3) * 64, DIN, sp, tid);
        stageB128(Bb + (s + 3) * 64, DIN, sp + 16384, tid);
        WAITVM(6);
      } else {
        WAITVM(0);
      }
      SBAR();
    }
  }

  int h = lane >> 4;
  #pragma unroll
  for (int mi = 0; mi < 4; ++mi)
    #pragma unroll
    for (int ni = 0; ni < 4; ++ni)
      #pragma unroll
      for (int r = 0; r < 4; ++r) {
        long row = r0 + wm * 64 + mi * 16 + h * 4 + r;
        int  col = c0 + wn * 64 + ni * 16 + (lane & 15);
        uB[(size_t)row * SDIM + col] = f2bf(acc[mi][ni][r]);
      }
  int cch = (int)((r0 >> 6) & 31) + wm;
  #pragma unroll
  for (int ni = 0; ni < 4; ++ni) {
    int col = c0 + wn * 64 + ni * 16 + (lane & 15);
    float a  = Adecay[col];
    float a2 = a * a, a3 = a2 * a;
    float A4 = a2 * a2;
    float A16 = A4 * A4; A16 = A16 * A16;
    float P16_2 = A16 * A16, P16_3 = P16_2 * A16;
    float Q4 = (h == 3) ? 1.f : (h == 2) ? A4 : (h == 1) ? A4 * A4 : A4 * A4 * A4;
    float cm0 = fmaf(acc[0][ni][0], a3, fmaf(acc[0][ni][1], a2, fmaf(acc[0][ni][2], a, acc[0][ni][3])));
    float cm1 = fmaf(acc[1][ni][0], a3, fmaf(acc[1][ni][1], a2, fmaf(acc[1][ni][2], a, acc[1][ni][3])));
    float cm2 = fmaf(acc[2][ni][0], a3, fmaf(acc[2][ni][1], a2, fmaf(acc[2][ni][2], a, acc[2][ni][3])));
    float cm3 = fmaf(acc[3][ni][0], a3, fmaf(acc[3][ni][1], a2, fmaf(acc[3][ni][2], a, acc[3][ni][3])));
    float L = fmaf(cm0, P16_3, fmaf(cm1, P16_2, fmaf(cm2, A16, cm3)));
    L *= Q4;
    L += __shfl_xor(L, 16);
    L += __shfl_xor(L, 32);
    if (h == 0) E[((size_t)b * NC + cch) * SDIM + col] = L;
  }
}

// ================= GEMM2: 256x128, 8 waves, 3-buf + MFMA/ds_read interleave ===
// (R10 structure, proven at 88.8 us)
__global__ __launch_bounds__(512, 2) void k_gemm_out(const short* __restrict__ hs,
                                                     const short* __restrict__ Xp,
                                                     const short* __restrict__ Ct,
                                                     const short* __restrict__ Mt,
                                                     float* __restrict__ out) {
  __shared__ __attribute__((aligned(16))) short lds[81920];
  short* const P0  = lds;
  short* const P1  = lds + 24576;
  short* const P2  = lds + 49152;
  short* const Xs0 = lds;
  short* const Xs1 = lds + 20480;
  short* const PM0 = lds + 57344;
  short* const PM1 = lds + 65536;
  short* const PM2 = lds + 73728;
  int tid = threadIdx.x, lane = tid & 63, w = tid >> 6;
  int wm = w >> 1, wn = w & 1;                  // 4M x 2N waves, 64x64 each
  int bid = blockIdx.x;
  int sw  = (bid & 7) * 32 + (bid >> 3);        // XCD-bijective over 256
  long r0 = (long)(sw & 63) * 256;
  int  c0 = (sw >> 6) * 128;
  int  b  = (int)(r0 >> 11);
  const short* hsA = hs + (size_t)r0 * SDIM;
  const short* CtB = Ct + (size_t)c0 * SDIM;
  const short* Xa  = Xp + (size_t)(r0 + 16 * (b + 1) - 16) * DIN;
  const short* MtB = Mt + (size_t)c0 * DIN;

  const f32x4 z4 = {0.f, 0.f, 0.f, 0.f};
  f32x4 acc[4][4];
  #pragma unroll
  for (int mi = 0; mi < 4; ++mi)
    #pragma unroll
    for (int ni = 0; ni < 4; ++ni) acc[mi][ni] = z4;

  Frags fr[2];

  // ---- prologue: stage tiles 0,1,2; read frags(0) ----
  stageA256(hsA,        SDIM, P0, tid);  stageB128(CtB,        SDIM, P0 + 16384, tid);
  stageA256(hsA + 64,   SDIM, P1, tid);  stageB128(CtB + 64,   SDIM, P1 + 16384, tid);
  stageA256(hsA + 128,  SDIM, P2, tid);  stageB128(CtB + 128,  SDIM, P2 + 16384, tid);
  WAITVM(6);                 // tiles 0,1 landed; tile 2 in flight
  SBAR();
  read_frags(fr[0], P0, 0, P0 + 16384, lane, wm, wn);

  // ---- phase 1: hs @ Ct^T, 16 steps ----
  #pragma unroll
  for (int s = 0; s < 16; ++s) {
    __builtin_amdgcn_s_setprio(1);
    mfma_frags(fr[s & 1], acc);
    if (s < 15) {
      const short* nb = ((s + 1) % 3 == 0) ? P0 : ((s + 1) % 3 == 1) ? P1 : P2;
      read_frags(fr[(s + 1) & 1], nb, 0, nb + 16384, lane, wm, wn);
    } else {
      read_frags(fr[0], Xs0, 16, PM0, lane, wm, wn);   // phase-2 g=0 frags
    }
    sgb_interleave();
    __builtin_amdgcn_s_setprio(0);
    LGKM0();
    SBAR();
    if (s <= 12) {
      short* sp = (s % 3 == 0) ? P0 : (s % 3 == 1) ? P1 : P2;
      stageA256(hsA + (s + 3) * 64, SDIM, sp, tid);
      stageB128(CtB + (s + 3) * 64, SDIM, sp + 16384, tid);
      WAITVM(6);               // drains tile s+2; tile s+3 in flight
    } else if (s == 13) {
      stageB128(MtB, DIN, PM0, tid);
      stageB128(MtB + (size_t)DOUT * DIN, DIN, PM1, tid);
      WAITVM(4);               // drains tile 15; M0,M1 in flight
    } else if (s == 14) {
      stageB128(MtB + (size_t)2 * DOUT * DIN, DIN, PM2, tid);
      stageX320(Xa, Xs0, tid);
      WAITVM(0);               // phase boundary: drain M0..M2 + X0
    }                           // s == 15: no stage, nothing outstanding
    SBAR();
  }

  // ---- phase 2: AR conv, 8 slices x 10 taps ----
  for (int k0 = 0; k0 < 8; ++k0) {
    int kc = k0 * 64;
    const short* xs = (k0 & 1) ? Xs1 : Xs0;
    short*       xn = (k0 & 1) ? Xs0 : Xs1;
    const short* q0 = (k0 % 3 == 0) ? PM0 : (k0 % 3 == 1) ? PM1 : PM2;
    const short* q1 = (k0 % 3 == 0) ? PM1 : (k0 % 3 == 1) ? PM2 : PM0;
    const short* q2 = (k0 % 3 == 0) ? PM2 : (k0 % 3 == 1) ? PM0 : PM1;
    #pragma unroll
    for (int j = 0; j < KX; ++j) {
      __builtin_amdgcn_s_setprio(1);
      mfma_frags(fr[j & 1], acc);
      bool do_read = (j < 9) || (k0 < 7);
      if (j < 9) {
        const short* mn = ((j + 1) % 3 == 0) ? q0 : ((j + 1) % 3 == 1) ? q1 : q2;
        read_frags(fr[(j + 1) & 1], xs, 15 - j, mn, lane, wm, wn);
      } else if (k0 < 7) {
        read_frags(fr[0], xn, 16, q1, lane, wm, wn);   // next slice tap 0
      }
      if (do_read) sgb_interleave();
      __builtin_amdgcn_s_setprio(0);
      LGKM0();
      SBAR();
      // stage M(j+3)
      if (j + 3 <= 9) {
        short* mw = (j % 3 == 0) ? (short*)q0 : (j % 3 == 1) ? (short*)q1 : (short*)q2;
        stageB128(MtB + (size_t)(j + 3) * DOUT * DIN + kc, DIN, mw, tid);
      } else if (k0 < 7) {
        short* mw = (j % 3 == 0) ? (short*)q0 : (j % 3 == 1) ? (short*)q1 : (short*)q2;
        stageB128(MtB + (size_t)(j - 7) * DOUT * DIN + kc + 64, DIN, mw, tid);
      }
      if (j == 1 && k0 < 7) stageX320(Xa + kc + 64, xn, tid);
      if (j == 1 || j == 2) {
        if (k0 < 7) { WAITVM(7); } else { WAITVM(2); }
      } else if (j >= 7) {
        if (k0 == 7) { WAITVM(0); } else { WAITVM(2); }
      } else {
        WAITVM(2);
      }
      SBAR();
    }
  }

  #pragma unroll
  for (int mi = 0; mi < 4; ++mi)
    #pragma unroll
    for (int ni = 0; ni < 4; ++ni)
      #pragma unroll
      for (int r = 0; r < 4; ++r) {
        long row = r0 + wm * 64 + mi * 16 + (lane >> 4) * 4 + r;
        int  col = c0 + wn * 64 + ni * 16 + (lane & 15);
        out[(size_t)row * DOUT + col] = acc[mi][ni][r];
      }
}

// ================= launch =================
extern "C" void kernel_launch(void* const* d_in, const int* in_sizes, int n_in,
                              void* d_out, int out_size, void* d_ws, size_t ws_size,
                              hipStream_t stream) {
  (void)in_sizes; (void)n_in; (void)out_size; (void)ws_size;
  const float* x  = (const float*)d_in[0];
  const float* h0 = (const float*)d_in[1];
  const float* A  = (const float*)d_in[2];
  const float* B  = (const float*)d_in[3];
  const float* C  = (const float*)d_in[4];
  const float* M  = (const float*)d_in[5];
  float* out = (float*)d_out;
  char* ws = (char*)d_ws;

  short* Xp  = (short*)(ws + OFF_XP);
  short* uB  = (short*)(ws + OFF_UB);
  short* hsb = (short*)(ws + OFF_HS);
  short* Bt  = (short*)(ws + OFF_BT);
  short* Ct  = (short*)(ws + OFF_CT);
  short* Mt  = (short*)(ws + OFF_MT);
  // scan scratch inside d_out (fully overwritten by k_gemm_out afterwards)
  float* E   = out;                    // B_SZ*NC*SDIM f32 = 1 MiB

  k_prep1<<<2560, 256, 0, stream>>>(x, B, Xp, Bt);
  k_gemm_uB<<<512, 512, 0, stream>>>(Xp, Bt, uB, A, E);
  k_scan_h<<<1792, 256, 0, stream>>>(uB, A, h0, E, hsb, C, M, Ct, Mt);
  k_gemm_out<<<256, 512, 0, stream>>>(hsb, Xp, Ct, Mt, out);
}

// Round 17
// 146.336 us; speedup vs baseline: 1.0372x; 1.0062x over previous
//
#include <hip/hip_runtime.h>

#define B_SZ   8
#define SEQ    2048
#define PSEQ   (SEQ+16)     // 16 zero pad rows before each batch
#define SDIM   1024
#define DIN    512
#define DOUT   512
#define KX     10
#define RTOT   (B_SZ*SEQ)   // 16384
#define LC     64
#define NC     (SEQ/LC)     // 32

typedef __attribute__((ext_vector_type(8))) short short8;
typedef __attribute__((ext_vector_type(4))) float f32x4;
typedef __attribute__((ext_vector_type(4))) unsigned short bfx4;

// ---- workspace layout (bytes). Xp has 64 slack rows for X-prefetch overread.
#define OFF_XP   0UL             // (B_SZ*PSEQ+64)*DIN*2 = 16,973,824
#define OFF_UB   16973824UL      // RTOT*SDIM*2 (bf16)   = 33,554,432
#define OFF_HS   50528256UL      // RTOT*SDIM*2 (bf16)   = 33,554,432
#define OFF_BT   84082688UL      // SDIM*DIN*2           = 1,048,576
#define OFF_CT   85131264UL      // DOUT*SDIM*2          = 1,048,576
#define OFF_MT   86179840UL      // KX*DOUT*DIN*2        = 5,242,880

__device__ __forceinline__ short f2bf(float f) {
  unsigned u = __builtin_bit_cast(unsigned, f);
  u += 0x7fffu + ((u >> 16) & 1u);   // RNE
  return (short)(u >> 16);
}
__device__ __forceinline__ float bf2f(unsigned short b) {
  return __builtin_bit_cast(float, (unsigned)b << 16);
}

#define GLOAD16(gp, lp) __builtin_amdgcn_global_load_lds( \
    (const __attribute__((address_space(1))) void*)(gp), \
    (__attribute__((address_space(3))) void*)(lp), 16, 0, 0)
#define WAITVM(n) asm volatile("s_waitcnt vmcnt(" #n ")" ::: "memory")
#define SBAR() __builtin_amdgcn_s_barrier()

// ================= shared GEMM pipeline building blocks =================
struct Frags { short8 a[4][2]; short8 b[4][2]; };

__device__ __forceinline__ void read_frags(Frags& f, const short* la, int aoff,
                                           const short* lb, int lane, int wm, int wn) {
  int lr = lane & 15, h = lane >> 4;
  #pragma unroll
  for (int kk = 0; kk < 2; ++kk) {
    int kslot = kk * 4 + h;
    #pragma unroll
    for (int mi = 0; mi < 4; ++mi) {
      int row = aoff + wm * 64 + mi * 16 + lr;
      f.a[mi][kk] = *reinterpret_cast<const short8*>(la + row * 64 + ((kslot ^ (row & 7)) << 3));
    }
    #pragma unroll
    for (int ni = 0; ni < 4; ++ni) {
      int row = wn * 64 + ni * 16 + lr;
      f.b[ni][kk] = *reinterpret_cast<const short8*>(lb + row * 64 + ((kslot ^ (row & 7)) << 3));
    }
  }
}

__device__ __forceinline__ void mfma_frags(const Frags& f, f32x4 acc[4][4]) {
  #pragma unroll
  for (int kk = 0; kk < 2; ++kk)
    #pragma unroll
    for (int mi = 0; mi < 4; ++mi)
      #pragma unroll
      for (int ni = 0; ni < 4; ++ni)
        acc[mi][ni] = __builtin_amdgcn_mfma_f32_16x16x32_bf16(f.a[mi][kk], f.b[ni][kk], acc[mi][ni], 0, 0, 0);
}

__device__ __forceinline__ void sgb_interleave() {
  #pragma unroll
  for (int i = 0; i < 16; ++i) {
    __builtin_amdgcn_sched_group_barrier(0x008, 2, 0);   // 2 MFMA
    __builtin_amdgcn_sched_group_barrier(0x100, 1, 0);   // 1 DS read
  }
}

__device__ __forceinline__ void stageA256(const short* __restrict__ g, int ld,
                                          short* l, int tid) {
  int rsub = tid >> 3;
  int slot = (tid & 7) ^ (rsub & 7);
  #pragma unroll
  for (int i = 0; i < 4; ++i) {
    int row = i * 64 + rsub;
    GLOAD16(g + (size_t)row * ld + slot * 8, l + row * 64 + (tid & 7) * 8);
  }
}
__device__ __forceinline__ void stageB128(const short* __restrict__ g, int ld,
                                          short* l, int tid) {
  int rsub = tid >> 3;
  int slot = (tid & 7) ^ (rsub & 7);
  #pragma unroll
  for (int i = 0; i < 2; ++i) {
    int row = i * 64 + rsub;
    GLOAD16(g + (size_t)row * ld + slot * 8, l + row * 64 + (tid & 7) * 8);
  }
}
__device__ __forceinline__ void stageX320(const short* __restrict__ g,
                                          short* l, int tid) {
  int rsub = tid >> 3;
  int slot = (tid & 7) ^ (rsub & 7);
  #pragma unroll
  for (int i = 0; i < 5; ++i) {
    int row = i * 64 + rsub;
    GLOAD16(g + (size_t)row * DIN + slot * 8, l + row * 64 + (tid & 7) * 8);
  }
}

// ================= prep1: conv+pad x | transpose B =================
__global__ void k_prep1(const float* __restrict__ x, const float* __restrict__ B,
                        short* __restrict__ Xp, short* __restrict__ Bt) {
  __shared__ float t[32][33];
  int blk = blockIdx.x, tid = threadIdx.x;
  if (blk < 2048) {
    const int NG = RTOT * (DIN / 8);
    const int NPAD = B_SZ * 16 * (DIN / 8);
    for (int g = blk * 256 + tid; g < NG + NPAD; g += 2048 * 256) {
      if (g < NG) {
        int r = g >> 6, c8 = g & 63;
        int b = r >> 11, tt = r & 2047;
        const float4* p = reinterpret_cast<const float4*>(x) + (size_t)g * 2;
        float4 f0 = p[0], f1 = p[1];
        short8 o;
        o[0]=f2bf(f0.x); o[1]=f2bf(f0.y); o[2]=f2bf(f0.z); o[3]=f2bf(f0.w);
        o[4]=f2bf(f1.x); o[5]=f2bf(f1.y); o[6]=f2bf(f1.z); o[7]=f2bf(f1.w);
        *reinterpret_cast<short8*>(Xp + ((size_t)(b * PSEQ + 16 + tt) * DIN + c8 * 8)) = o;
      } else {
        int idx = g - NG;
        int b = idx >> 10, rem = idx & 1023;
        int row16 = rem >> 6, c8 = rem & 63;
        const short8 z = {0,0,0,0,0,0,0,0};
        *reinterpret_cast<short8*>(Xp + ((size_t)(b * PSEQ + row16) * DIN + c8 * 8)) = z;
      }
    }
  } else {
    int idx = blk - 2048;                 // B: [DIN x SDIM] -> Bt [SDIM][DIN]
    int bx = (idx & 31) * 32, by = (idx >> 5) * 32;
    int tx = tid & 31, ty = tid >> 5;
    #pragma unroll
    for (int j = 0; j < 32; j += 8)
      t[ty + j][tx] = B[(size_t)(by + ty + j) * SDIM + (bx + tx)];
    __syncthreads();
    #pragma unroll
    for (int j = 0; j < 32; j += 8)
      Bt[(size_t)(bx + ty + j) * DIN + (by + tx)] = f2bf(t[tx][ty + j]);
  }
}

// ================= scan_h (+S folded) | transpose C | prep M =================
__global__ void k_scan_h(const short* __restrict__ uB, const float* __restrict__ A,
                         const float* __restrict__ h0, const float* __restrict__ E,
                         short* __restrict__ hs,
                         const float* __restrict__ C, const float* __restrict__ M,
                         short* __restrict__ Ct, short* __restrict__ Mt) {
  __shared__ float t[32][33];
  int blk = blockIdx.x, tid = threadIdx.x;
  if (blk < 256) {
    int b = blk >> 5, c = blk & 31;
    int s0 = tid * 4;
    float a[4], h[4], ap[4];
    #pragma unroll
    for (int j = 0; j < 4; ++j) {
      a[j] = A[s0 + j];
      float p = a[j];
      #pragma unroll
      for (int q = 0; q < 6; ++q) p *= p;   // a^64
      ap[j] = p;
      h[j] = h0[s0 + j];
    }
    const float* Eb = E + (size_t)b * NC * SDIM + s0;
    for (int c2 = 0; c2 < c; ++c2) {
      float4 ev = *reinterpret_cast<const float4*>(Eb + (size_t)c2 * SDIM);
      h[0] = fmaf(ap[0], h[0], ev.x);
      h[1] = fmaf(ap[1], h[1], ev.y);
      h[2] = fmaf(ap[2], h[2], ev.z);
      h[3] = fmaf(ap[3], h[3], ev.w);
    }
    const short* base = uB + ((size_t)b * SEQ + (size_t)c * LC) * SDIM + s0;
    short* hbase = hs + ((size_t)b * SEQ + (size_t)c * LC) * SDIM + s0;
    for (int tt = 0; tt < LC; ++tt) {
      bfx4 v = *reinterpret_cast<const bfx4*>(base + (size_t)tt * SDIM);
      bfx4 o;
      #pragma unroll
      for (int j = 0; j < 4; ++j) {
        h[j] = fmaf(a[j], h[j], bf2f(v[j]));
        o[j] = (unsigned short)f2bf(h[j]);
      }
      *reinterpret_cast<bfx4*>(hbase + (size_t)tt * SDIM) = o;
    }
  } else if (blk < 768) {
    int idx = blk - 256;                  // C: [SDIM x DOUT] -> Ct [DOUT][SDIM]
    int bx = (idx & 15) * 32, by = (idx >> 4) * 32;
    int tx = tid & 31, ty = tid >> 5;
    #pragma unroll
    for (int j = 0; j < 32; j += 8)
      t[ty + j][tx] = C[(size_t)(by + ty + j) * DOUT + (bx + tx)];
    __syncthreads();
    #pragma unroll
    for (int j = 0; j < 32; j += 8)
      Ct[(size_t)(bx + ty + j) * SDIM + (by + tx)] = f2bf(t[tx][ty + j]);
  } else {
    int idx = (blk - 768) * 256 + tid;    // Mt[t][o][i] = bf16(M[o][i][t])
    if (idx < DOUT * DIN) {
      int o = idx / DIN, i = idx - o * DIN;
      const float* src = M + ((size_t)o * DIN + i) * KX;
      #pragma unroll
      for (int tt = 0; tt < KX; ++tt)
        Mt[((size_t)tt * DOUT + o) * DIN + i] = f2bf(src[tt]);
    }
  }
}

// ================= GEMM1: 256x128, 8 waves, 3-buf ring ======================
__global__ __launch_bounds__(512, 2) void k_gemm_uB(const short* __restrict__ Xp,
                                                    const short* __restrict__ Bt,
                                                    short* __restrict__ uB,
                                                    const float* __restrict__ Adecay,
                                                    float* __restrict__ E) {
  __shared__ __attribute__((aligned(16))) short lds[73728];   // 3 x (16384A + 8192B)
  short* const P0 = lds;
  short* const P1 = lds + 24576;
  short* const P2 = lds + 49152;
  int tid = threadIdx.x, lane = tid & 63, w = tid >> 6;
  int wm = w >> 1, wn = w & 1;                 // 4M x 2N waves, 64x64 each
  int bid = blockIdx.x;
  long r0 = (long)(bid & 63) * 256;
  int  c0 = (bid >> 6) * 128;
  int  b  = (int)(r0 >> 11);
  const short* Aa = Xp + (size_t)(r0 + 16 * (b + 1)) * DIN;
  const short* Bb = Bt + (size_t)c0 * DIN;

  const f32x4 z4 = {0.f, 0.f, 0.f, 0.f};
  f32x4 acc[4][4];
  #pragma unroll
  for (int mi = 0; mi < 4; ++mi)
    #pragma unroll
    for (int ni = 0; ni < 4; ++ni) acc[mi][ni] = z4;

  Frags fr[2];

  stageA256(Aa,       DIN, P0, tid);  stageB128(Bb,       DIN, P0 + 16384, tid);
  stageA256(Aa + 64,  DIN, P1, tid);  stageB128(Bb + 64,  DIN, P1 + 16384, tid);
  stageA256(Aa + 128, DIN, P2, tid);  stageB128(Bb + 128, DIN, P2 + 16384, tid);
  WAITVM(6);
  SBAR();
  read_frags(fr[0], P0, 0, P0 + 16384, lane, wm, wn);

  #pragma unroll
  for (int s = 0; s < 8; ++s) {
    __builtin_amdgcn_s_setprio(1);
    mfma_frags(fr[s & 1], acc);
    if (s < 7) {
      const short* nb = ((s + 1) % 3 == 0) ? P0 : ((s + 1) % 3 == 1) ? P1 : P2;
      read_frags(fr[(s + 1) & 1], nb, 0, nb + 16384, lane, wm, wn);
      sgb_interleave();
    }
    __builtin_amdgcn_s_setprio(0);
    if (s < 7) {
      SBAR();
      if (s <= 4) {
        short* sp = (s % 3 == 0) ? P0 : (s % 3 == 1) ? P1 : P2;
        stageA256(Aa + (s + 3) * 64, DIN, sp, tid);
        stageB128(Bb + (s + 3) * 64, DIN, sp + 16384, tid);
        WAITVM(6);
      } else {
        WAITVM(0);
      }
      SBAR();
    }
  }

  int h = lane >> 4;
  #pragma unroll
  for (int mi = 0; mi < 4; ++mi)
    #pragma unroll
    for (int ni = 0; ni < 4; ++ni)
      #pragma unroll
      for (int r = 0; r < 4; ++r) {
        long row = r0 + wm * 64 + mi * 16 + h * 4 + r;
        int  col = c0 + wn * 64 + ni * 16 + (lane & 15);
        uB[(size_t)row * SDIM + col] = f2bf(acc[mi][ni][r]);
      }
  int cch = (int)((r0 >> 6) & 31) + wm;
  #pragma unroll
  for (int ni = 0; ni < 4; ++ni) {
    int col = c0 + wn * 64 + ni * 16 + (lane & 15);
    float a  = Adecay[col];
    float a2 = a * a, a3 = a2 * a;
    float A4 = a2 * a2;
    float A16 = A4 * A4; A16 = A16 * A16;
    float P16_2 = A16 * A16, P16_3 = P16_2 * A16;
    float Q4 = (h == 3) ? 1.f : (h == 2) ? A4 : (h == 1) ? A4 * A4 : A4 * A4 * A4;
    float cm0 = fmaf(acc[0][ni][0], a3, fmaf(acc[0][ni][1], a2, fmaf(acc[0][ni][2], a, acc[0][ni][3])));
    float cm1 = fmaf(acc[1][ni][0], a3, fmaf(acc[1][ni][1], a2, fmaf(acc[1][ni][2], a, acc[1][ni][3])));
    float cm2 = fmaf(acc[2][ni][0], a3, fmaf(acc[2][ni][1], a2, fmaf(acc[2][ni][2], a, acc[2][ni][3])));
    float cm3 = fmaf(acc[3][ni][0], a3, fmaf(acc[3][ni][1], a2, fmaf(acc[3][ni][2], a, acc[3][ni][3])));
    float L = fmaf(cm0, P16_3, fmaf(cm1, P16_2, fmaf(cm2, A16, cm3)));
    L *= Q4;
    L += __shfl_xor(L, 16);
    L += __shfl_xor(L, 32);
    if (h == 0) E[((size_t)b * NC + cch) * SDIM + col] = L;
  }
}

// ================= GEMM2: 256x128, 8 waves, 3-buf + MFMA/ds_read interleave ===
// R10 structure minus per-step lgkmcnt(0) drain (compiler waitcnts cover the
// fr-register deps; buffer-overwrite hazard closed by the consuming MFMA's
// auto-wait preceding the release barrier in every wave).
__global__ __launch_bounds__(512, 2) void k_gemm_out(const short* __restrict__ hs,
                                                     const short* __restrict__ Xp,
                                                     const short* __restrict__ Ct,
                                                     const short* __restrict__ Mt,
                                                     float* __restrict__ out) {
  __shared__ __attribute__((aligned(16))) short lds[81920];
  short* const P0  = lds;
  short* const P1  = lds + 24576;
  short* const P2  = lds + 49152;
  short* const Xs0 = lds;
  short* const Xs1 = lds + 20480;
  short* const PM0 = lds + 57344;
  short* const PM1 = lds + 65536;
  short* const PM2 = lds + 73728;
  int tid = threadIdx.x, lane = tid & 63, w = tid >> 6;
  int wm = w >> 1, wn = w & 1;                  // 4M x 2N waves, 64x64 each
  int bid = blockIdx.x;
  int sw  = (bid & 7) * 32 + (bid >> 3);        // XCD-bijective over 256
  long r0 = (long)(sw & 63) * 256;
  int  c0 = (sw >> 6) * 128;
  int  b  = (int)(r0 >> 11);
  const short* hsA = hs + (size_t)r0 * SDIM;
  const short* CtB = Ct + (size_t)c0 * SDIM;
  const short* Xa  = Xp + (size_t)(r0 + 16 * (b + 1) - 16) * DIN;
  const short* MtB = Mt + (size_t)c0 * DIN;

  const f32x4 z4 = {0.f, 0.f, 0.f, 0.f};
  f32x4 acc[4][4];
  #pragma unroll
  for (int mi = 0; mi < 4; ++mi)
    #pragma unroll
    for (int ni = 0; ni < 4; ++ni) acc[mi][ni] = z4;

  Frags fr[2];

  // ---- prologue: stage tiles 0,1,2; read frags(0) ----
  stageA256(hsA,        SDIM, P0, tid);  stageB128(CtB,        SDIM, P0 + 16384, tid);
  stageA256(hsA + 64,   SDIM, P1, tid);  stageB128(CtB + 64,   SDIM, P1 + 16384, tid);
  stageA256(hsA + 128,  SDIM, P2, tid);  stageB128(CtB + 128,  SDIM, P2 + 16384, tid);
  WAITVM(6);                 // tiles 0,1 landed; tile 2 in flight
  SBAR();
  read_frags(fr[0], P0, 0, P0 + 16384, lane, wm, wn);

  // ---- phase 1: hs @ Ct^T, 16 steps ----
  #pragma unroll
  for (int s = 0; s < 16; ++s) {
    __builtin_amdgcn_s_setprio(1);
    mfma_frags(fr[s & 1], acc);
    if (s < 15) {
      const short* nb = ((s + 1) % 3 == 0) ? P0 : ((s + 1) % 3 == 1) ? P1 : P2;
      read_frags(fr[(s + 1) & 1], nb, 0, nb + 16384, lane, wm, wn);
    } else {
      read_frags(fr[0], Xs0, 16, PM0, lane, wm, wn);   // phase-2 g=0 frags
    }
    sgb_interleave();
    __builtin_amdgcn_s_setprio(0);
    SBAR();
    if (s <= 12) {
      short* sp = (s % 3 == 0) ? P0 : (s % 3 == 1) ? P1 : P2;
      stageA256(hsA + (s + 3) * 64, SDIM, sp, tid);
      stageB128(CtB + (s + 3) * 64, SDIM, sp + 16384, tid);
      WAITVM(6);               // drains tile s+2; tile s+3 in flight
    } else if (s == 13) {
      stageB128(MtB, DIN, PM0, tid);
      stageB128(MtB + (size_t)DOUT * DIN, DIN, PM1, tid);
      WAITVM(4);               // drains tile 15; M0,M1 in flight
    } else if (s == 14) {
      stageB128(MtB + (size_t)2 * DOUT * DIN, DIN, PM2, tid);
      stageX320(Xa, Xs0, tid);
      WAITVM(0);               // phase boundary: drain M0..M2 + X0
    }                           // s == 15: no stage, nothing outstanding
    SBAR();
  }

  // ---- phase 2: AR conv, 8 slices x 10 taps ----
  for (int k0 = 0; k0 < 8; ++k0) {
    int kc = k0 * 64;
    const short* xs = (k0 & 1) ? Xs1 : Xs0;
    short*       xn = (k0 & 1) ? Xs0 : Xs1;
    const short* q0 = (k0 % 3 == 0) ? PM0 : (k0 % 3 == 1) ? PM1 : PM2;
    const short* q1 = (k0 % 3 == 0) ? PM1 : (k0 % 3 == 1) ? PM2 : PM0;
    const short* q2 = (k0 % 3 == 0) ? PM2 : (k0 % 3 == 1) ? PM0 : PM1;
    #pragma unroll
    for (int j = 0; j < KX; ++j) {
      __builtin_amdgcn_s_setprio(1);
      mfma_frags(fr[j & 1], acc);
      bool do_read = (j < 9) || (k0 < 7);
      if (j < 9) {
        const short* mn = ((j + 1) % 3 == 0) ? q0 : ((j + 1) % 3 == 1) ? q1 : q2;
        read_frags(fr[(j + 1) & 1], xs, 15 - j, mn, lane, wm, wn);
      } else if (k0 < 7) {
        read_frags(fr[0], xn, 16, q1, lane, wm, wn);   // next slice tap 0
      }
      if (do_read) sgb_interleave();
      __builtin_amdgcn_s_setprio(0);
      SBAR();
      // stage M(j+3)
      if (j + 3 <= 9) {
        short* mw = (j % 3 == 0) ? (short*)q0 : (j % 3 == 1) ? (short*)q1 : (short*)q2;
        stageB128(MtB + (size_t)(j + 3) * DOUT * DIN + kc, DIN, mw, tid);
      } else if (k0 < 7) {
        short* mw = (j % 3 == 0) ? (short*)q0 : (j % 3 == 1) ? (short*)q1 : (short*)q2;
        stageB128(MtB + (size_t)(j - 7) * DOUT * DIN + kc + 64, DIN, mw, tid);
      }
      if (j == 1 && k0 < 7) stageX320(Xa + kc + 64, xn, tid);
      if (j == 1 || j == 2) {
        if (k0 < 7) { WAITVM(7); } else { WAITVM(2); }
      } else if (j >= 7) {
        if (k0 == 7) { WAITVM(0); } else { WAITVM(2); }
      } else {
        WAITVM(2);
      }
      SBAR();
    }
  }

  #pragma unroll
  for (int mi = 0; mi < 4; ++mi)
    #pragma unroll
    for (int ni = 0; ni < 4; ++ni)
      #pragma unroll
      for (int r = 0; r < 4; ++r) {
        long row = r0 + wm * 64 + mi * 16 + (lane >> 4) * 4 + r;
        int  col = c0 + wn * 64 + ni * 16 + (lane & 15);
        out[(size_t)row * DOUT + col] = acc[mi][ni][r];
      }
}

// ================= launch =================
extern "C" void kernel_launch(void* const* d_in, const int* in_sizes, int n_in,
                              void* d_out, int out_size, void* d_ws, size_t ws_size,
                              hipStream_t stream) {
  (void)in_sizes; (void)n_in; (void)out_size; (void)ws_size;
  const float* x  = (const float*)d_in[0];
  const float* h0 = (const float*)d_in[1];
  const float* A  = (const float*)d_in[2];
  const float* B  = (const float*)d_in[3];
  const float* C  = (const float*)d_in[4];
  const float* M  = (const float*)d_in[5];
  float* out = (float*)d_out;
  char* ws = (char*)d_ws;

  short* Xp  = (short*)(ws + OFF_XP);
  short* uB  = (short*)(ws + OFF_UB);
  short* hsb = (short*)(ws + OFF_HS);
  short* Bt  = (short*)(ws + OFF_BT);
  short* Ct  = (short*)(ws + OFF_CT);
  short* Mt  = (short*)(ws + OFF_MT);
  // scan scratch inside d_out (fully overwritten by k_gemm_out afterwards)
  float* E   = out;                    // B_SZ*NC*SDIM f32 = 1 MiB

  k_prep1<<<2560, 256, 0, stream>>>(x, B, Xp, Bt);
  k_gemm_uB<<<512, 512, 0, stream>>>(Xp, Bt, uB, A, E);
  k_scan_h<<<1792, 256, 0, stream>>>(uB, A, h0, E, hsb, C, M, Ct, Mt);
  k_gemm_out<<<256, 512, 0, stream>>>(hsb, Xp, Ct, Mt, out);
}